// Round 4
// baseline (1471.064 us; speedup 1.0000x reference)
//
#include <hip/hip_runtime.h>

#define DIM   1536
#define NQKV  4608
#define NH    24
#define HD    64
#define BATCH 4
#define SEQ   4096
#define ROWS  16384   // BATCH*SEQ

typedef _Float16 f16x8 __attribute__((ext_vector_type(8)));
typedef float    f32x4 __attribute__((ext_vector_type(4)));

__device__ __forceinline__ void gload_lds16(const void* g, void* l) {
  __builtin_amdgcn_global_load_lds(
      (const __attribute__((address_space(1))) unsigned int*)g,
      (__attribute__((address_space(3))) unsigned int*)l, 16, 0, 0);
}
__device__ __forceinline__ float fexp2(float x) {
#if __has_builtin(__builtin_amdgcn_exp2f)
  return __builtin_amdgcn_exp2f(x);
#else
  return exp2f(x);
#endif
}

// scale * log2(e), folded into q inside rms_rope
#define QSCALE 0.18033688011112042f

// ---------------- kernel 0: X fp32 -> fp16 --------------------------------
__global__ __launch_bounds__(256) void convert_x(const float* __restrict__ X,
                                                 _Float16* __restrict__ Xh) {
  const int i = (blockIdx.x * 256 + threadIdx.x) * 8;
  float4 a = *(const float4*)(X + i);
  float4 b = *(const float4*)(X + i + 4);
  f16x8 h;
  h[0] = (_Float16)a.x; h[1] = (_Float16)a.y; h[2] = (_Float16)a.z; h[3] = (_Float16)a.w;
  h[4] = (_Float16)b.x; h[5] = (_Float16)b.y; h[6] = (_Float16)b.z; h[7] = (_Float16)b.w;
  *(f16x8*)(Xh + i) = h;
}

// ---------------- kernel 1: W (K x N) fp32 -> Wt (N x K) fp16 -------------
__global__ __launch_bounds__(256) void transpose_w(const float* __restrict__ W,
                                                   _Float16* __restrict__ Wt) {
  __shared__ float tile[32][33];
  const int tx = threadIdx.x, ty = threadIdx.y;        // 32 x 8
  const int k0 = blockIdx.y * 32, n0 = blockIdx.x * 32;
  #pragma unroll
  for (int i = 0; i < 32; i += 8)
    tile[ty + i][tx] = W[(size_t)(k0 + ty + i) * NQKV + n0 + tx];
  __syncthreads();
  #pragma unroll
  for (int i = 0; i < 32; i += 8)
    Wt[(size_t)(n0 + ty + i) * DIM + k0 + tx] = (_Float16)tile[tx][ty + i];
}

// ---------------- kernel 2: QKV = Xh @ Wt^T + b  (fp16 MFMA) --------------
__global__ __launch_bounds__(256) void qkv_gemm(const _Float16* __restrict__ Xh,
                                                const _Float16* __restrict__ Wt,
                                                const float* __restrict__ Bias,
                                                _Float16* __restrict__ QKV) {
  __shared__ _Float16 As[128 * 64];
  __shared__ _Float16 Bs[128 * 64];
  const int w    = threadIdx.x >> 6;
  const int lane = threadIdx.x & 63;
  const int lr   = lane >> 3, lc = lane & 7;
  const int quad = lane >> 4, l15 = lane & 15;
  const int m0 = blockIdx.y * 128;
  const int n0 = blockIdx.x * 128;
  const int waveR = (w >> 1) * 64;
  const int waveC = (w & 1) * 64;

  f32x4 acc[4][4];
  #pragma unroll
  for (int i = 0; i < 4; i++)
    #pragma unroll
    for (int j = 0; j < 4; j++) acc[i][j] = (f32x4){0.f, 0.f, 0.f, 0.f};

  for (int kt = 0; kt < DIM / 64; ++kt) {
    const int k0 = kt * 64;
    #pragma unroll
    for (int i = 0; i < 4; ++i) {
      const int rr = w * 32 + i * 8;
      gload_lds16(Xh + (size_t)(m0 + rr + lr) * DIM + k0 + lc * 8, &As[rr * 64]);
      gload_lds16(Wt + (size_t)(n0 + rr + lr) * DIM + k0 + lc * 8, &Bs[rr * 64]);
    }
    __syncthreads();
    #pragma unroll
    for (int ks = 0; ks < 2; ++ks) {
      f16x8 aF[4], bF[4];
      #pragma unroll
      for (int t = 0; t < 4; t++)
        aF[t] = *(const f16x8*)&As[(waveR + t * 16 + l15) * 64 + ks * 32 + quad * 8];
      #pragma unroll
      for (int t = 0; t < 4; t++)
        bF[t] = *(const f16x8*)&Bs[(waveC + t * 16 + l15) * 64 + ks * 32 + quad * 8];
      #pragma unroll
      for (int mt = 0; mt < 4; mt++)
        #pragma unroll
        for (int nt = 0; nt < 4; nt++)
          acc[mt][nt] = __builtin_amdgcn_mfma_f32_16x16x32_f16(aF[mt], bF[nt], acc[mt][nt], 0, 0, 0);
    }
    __syncthreads();
  }
  #pragma unroll
  for (int nt = 0; nt < 4; nt++) {
    const int n = n0 + waveC + nt * 16 + l15;
    const float bias = Bias[n];
    #pragma unroll
    for (int mt = 0; mt < 4; mt++) {
      const int mBase = m0 + waveR + mt * 16 + quad * 4;
      #pragma unroll
      for (int r = 0; r < 4; r++)
        QKV[(size_t)(mBase + r) * NQKV + n] = (_Float16)(acc[mt][nt][r] + bias);
    }
  }
}

// ---------------- kernel 3: RMSNorm(q,k) + RoPE, in place -----------------
__global__ __launch_bounds__(256) void rms_rope(_Float16* __restrict__ QKV,
                                                const float* __restrict__ Cos,
                                                const float* __restrict__ Sin) {
  const int gw   = blockIdx.x * 4 + (threadIdx.x >> 6);
  const int lane = threadIdx.x & 63;
  const int row  = gw / NH;
  const int h    = gw - row * NH;
  const int s    = row & (SEQ - 1);

  _Float16* p = QKV + (size_t)row * NQKV + h * HD;
  float q = (float)p[lane];
  float k = (float)p[DIM + lane];

  float sq = q * q, sk = k * k;
  #pragma unroll
  for (int off = 1; off < 64; off <<= 1) {
    sq += __shfl_xor(sq, off);
    sk += __shfl_xor(sk, off);
  }
  q *= rsqrtf(sq * (1.f / 64.f) + 1e-6f);
  k *= rsqrtf(sk * (1.f / 64.f) + 1e-6f);

  const float c  = Cos[s * HD + lane];
  const float si = Sin[s * HD + lane];
  const float qp = __shfl_xor(q, 1);
  const float kp = __shfl_xor(k, 1);
  float oq, ok;
  if (lane & 1) { oq = q * c + qp * si; ok = k * c + kp * si; }
  else          { oq = q * c - qp * si; ok = k * c - kp * si; }

  p[lane]       = (_Float16)(oq * QSCALE);
  p[DIM + lane] = (_Float16)ok;
}

// ---------------- kernel 4: flash attention, BR=256, prefetched -----------
// 64 q-rows per wave; static-max softmax (p = exp2(score), score <= 11.54);
// row-sum via ones-column MFMA; next K/V tile prefetched into registers
// during compute so global latency overlaps MFMA/LDS work.
#define LSTR 72
__global__ __launch_bounds__(256) void flash_attn(const _Float16* __restrict__ QKV,
                                                  float* __restrict__ Out) {
  __shared__ __align__(16) _Float16 sm[2 * 64 * LSTR + 4 * 64 * LSTR];
  _Float16* Ks  = sm;
  _Float16* Vts = sm + 64 * LSTR;
  const int w = threadIdx.x >> 6;
  _Float16* Ps = sm + 2 * 64 * LSTR + w * 64 * LSTR;   // wave-private, 64 rows
  const int lane = threadIdx.x & 63;
  const int quad = lane >> 4, l15 = lane & 15;
  const int bh = blockIdx.y;
  const int qt = blockIdx.x;
  const int b  = bh / NH;
  const int h  = bh - b * NH;
  const size_t rowb = (size_t)b * SEQ * NQKV + (size_t)h * HD;  // + s*NQKV per token

  // Q fragments (A-layout) straight from global, live whole kernel
  f16x8 qreg[4][2];
  #pragma unroll
  for (int mt = 0; mt < 4; mt++)
    #pragma unroll
    for (int ks = 0; ks < 2; ks++) {
      const int row = qt * 256 + w * 64 + mt * 16 + l15;
      qreg[mt][ks] = *(const f16x8*)(QKV + rowb + (size_t)row * NQKV + ks * 32 + quad * 8);
    }

  // ones B-fragment: column n==0 of the ghost V-tile is all ones
  f16x8 onesF;
  {
    const _Float16 one = (_Float16)(l15 == 0 ? 1.0f : 0.0f);
    #pragma unroll
    for (int j = 0; j < 8; j++) onesF[j] = one;
  }

  f32x4 o[4][4], o4[4];
  #pragma unroll
  for (int mt = 0; mt < 4; mt++) {
    o4[mt] = (f32x4){0.f, 0.f, 0.f, 0.f};
    #pragma unroll
    for (int t = 0; t < 4; t++) o[mt][t] = (f32x4){0.f, 0.f, 0.f, 0.f};
  }

  // staging address helpers
  const int kr  = threadIdx.x >> 3;            // 0..31  (row within half-tile)
  const int kc0 = (threadIdx.x & 7) * 8;       // 0..56  (col)
  const int vc0base = w * 16;                  // this wave's 16 d-columns of V

  // ---- prologue: stage tile 0 directly ----
  #pragma unroll
  for (int i = 0; i < 2; i++) {
    const int r = kr + i * 32;
    *(uint4*)&Ks[r * LSTR + kc0] =
        *(const uint4*)(QKV + rowb + (size_t)r * NQKV + DIM + kc0);
  }
  #pragma unroll
  for (int i = 0; i < 2; i++) {
    const int c0 = vc0base + i * 8;
    union { uint4 v; _Float16 u[8]; } d;
    d.v = *(const uint4*)(QKV + rowb + (size_t)lane * NQKV + 2 * DIM + c0);
    #pragma unroll
    for (int j = 0; j < 8; j++) Vts[(c0 + j) * LSTR + lane] = d.u[j];
  }

  for (int kt = 0; kt < SEQ / 64; ++kt) {
    __syncthreads();   // staged tile kt visible

    // ---- prefetch next tile into registers (overlaps with compute) ----
    const int ktn = (kt + 1 < SEQ / 64) ? kt + 1 : kt;
    uint4 kpre[2], vpre[2];
    #pragma unroll
    for (int i = 0; i < 2; i++)
      kpre[i] = *(const uint4*)(QKV + rowb + (size_t)(ktn * 64 + kr + i * 32) * NQKV + DIM + kc0);
    #pragma unroll
    for (int i = 0; i < 2; i++)
      vpre[i] = *(const uint4*)(QKV + rowb + (size_t)(ktn * 64 + lane) * NQKV + 2 * DIM + vc0base + i * 8);

    // ---- S = Q K^T : 64 q-rows x 64 keys per wave ----
    f32x4 sacc[4][4];
    #pragma unroll
    for (int mt = 0; mt < 4; mt++)
      #pragma unroll
      for (int t = 0; t < 4; t++) sacc[mt][t] = (f32x4){0.f, 0.f, 0.f, 0.f};
    #pragma unroll
    for (int ks = 0; ks < 2; ks++) {
      f16x8 bF[4];
      #pragma unroll
      for (int t = 0; t < 4; t++)
        bF[t] = *(const f16x8*)&Ks[(t * 16 + l15) * LSTR + ks * 32 + quad * 8];
      #pragma unroll
      for (int mt = 0; mt < 4; mt++)
        #pragma unroll
        for (int t = 0; t < 4; t++)
          sacc[mt][t] = __builtin_amdgcn_mfma_f32_16x16x32_f16(qreg[mt][ks], bF[t], sacc[mt][t], 0, 0, 0);
    }

    // ---- p = exp2(score), write fp16 P to wave-private LDS ----
    #pragma unroll
    for (int mt = 0; mt < 4; mt++)
      #pragma unroll
      for (int t = 0; t < 4; t++)
        #pragma unroll
        for (int r = 0; r < 4; r++) {
          const _Float16 ph = (_Float16)fexp2(sacc[mt][t][r]);
          Ps[(mt * 16 + quad * 4 + r) * LSTR + t * 16 + l15] = ph;
        }

    // ---- O += P V ; Sigma p via ones-column ----
    #pragma unroll
    for (int ks = 0; ks < 2; ks++) {
      f16x8 pF[4];
      #pragma unroll
      for (int mt = 0; mt < 4; mt++)
        pF[mt] = *(const f16x8*)&Ps[(mt * 16 + l15) * LSTR + ks * 32 + quad * 8];
      #pragma unroll
      for (int t = 0; t < 4; t++) {
        f16x8 vF = *(const f16x8*)&Vts[(t * 16 + l15) * LSTR + ks * 32 + quad * 8];
        #pragma unroll
        for (int mt = 0; mt < 4; mt++)
          o[mt][t] = __builtin_amdgcn_mfma_f32_16x16x32_f16(pF[mt], vF, o[mt][t], 0, 0, 0);
      }
      #pragma unroll
      for (int mt = 0; mt < 4; mt++)
        o4[mt] = __builtin_amdgcn_mfma_f32_16x16x32_f16(pF[mt], onesF, o4[mt], 0, 0, 0);
    }

    __syncthreads();   // all waves done reading Ks/Vts

    // ---- commit prefetched tile to LDS ----
    #pragma unroll
    for (int i = 0; i < 2; i++)
      *(uint4*)&Ks[(kr + i * 32) * LSTR + kc0] = kpre[i];
    #pragma unroll
    for (int i = 0; i < 2; i++) {
      const int c0 = vc0base + i * 8;
      union { uint4 v; _Float16 u[8]; } d;
      d.v = vpre[i];
      #pragma unroll
      for (int j = 0; j < 8; j++) Vts[(c0 + j) * LSTR + lane] = d.u[j];
    }
  }

  // ---- epilogue: lrow = Sigma p at lanes l15==0 of ones-tile ----
  #pragma unroll
  for (int mt = 0; mt < 4; mt++) {
    float lrow[4];
    #pragma unroll
    for (int r = 0; r < 4; r++) lrow[r] = __shfl(o4[mt][r], lane & 48);
    #pragma unroll
    for (int t = 0; t < 4; t++)
      #pragma unroll
      for (int r = 0; r < 4; r++) {
        const int srow = qt * 256 + w * 64 + mt * 16 + quad * 4 + r;
        const int d = t * 16 + l15;
        Out[((size_t)(b * SEQ + srow)) * DIM + h * HD + d] = o[mt][t][r] / lrow[r];
      }
  }
}

// ---------------- launch --------------------------------------------------
extern "C" void kernel_launch(void* const* d_in, const int* in_sizes, int n_in,
                              void* d_out, int out_size, void* d_ws, size_t ws_size,
                              hipStream_t stream) {
  const float* X    = (const float*)d_in[0];
  const float* Cos  = (const float*)d_in[1];
  const float* Sin  = (const float*)d_in[2];
  const float* W    = (const float*)d_in[3];
  const float* Bias = (const float*)d_in[4];
  float* Out = (float*)d_out;

  char* ws = (char*)d_ws;
  _Float16* Xh  = (_Float16*)(ws);                  // 50,331,648 B
  _Float16* Wt  = (_Float16*)(ws + 50331648);       // 14,155,776 B
  _Float16* QKV = (_Float16*)(ws + 64487424);       // 150,994,944 B (end 215,482,368)

  convert_x  <<<dim3(ROWS * DIM / (8 * 256)), 256, 0, stream>>>(X, Xh);
  transpose_w<<<dim3(NQKV / 32, DIM / 32), dim3(32, 8), 0, stream>>>(W, Wt);
  qkv_gemm   <<<dim3(NQKV / 128, ROWS / 128), 256, 0, stream>>>(Xh, Wt, Bias, QKV);
  rms_rope   <<<dim3(ROWS * NH / 4), 256, 0, stream>>>(QKV, Cos, Sin);
  flash_attn <<<dim3(SEQ / 256, BATCH * NH), 256, 0, stream>>>(QKV, Out);
}